// Round 18
// baseline (124.397 us; speedup 1.0000x reference)
//
#include <hip/hip_runtime.h>

typedef __fp16 h2 __attribute__((ext_vector_type(2)));
typedef float f4 __attribute__((ext_vector_type(4)));

static __device__ __forceinline__ unsigned pkrtz(float a, float b) {
    union { h2 v; unsigned u; } cv;
    cv.v = __builtin_amdgcn_cvt_pkrtz(a, b);
    return cv.u;
}
static __device__ __forceinline__ h2 as_h2(unsigned u) {
    union { unsigned u; h2 v; } cv; cv.u = u; return cv.v;
}

// ---- prep: pack weights into f16-pair dwords in d_ws -------------------------
//   [j*6 + i]      i<5 : (W1[j][2i], W1[j][2i+1]) f16 pair       (j in 0..39)
//   [j*6 + 5]          : b1[j] as f32 bits
//   [240 + p*4+o]      : (W2[o][2p], W2[o][2p+1]) f16 pair       (p in 0..19)
//   [320 + o]          : b2[o] as f32 bits
__global__ void prep_kernel(const float* __restrict__ W1, const float* __restrict__ b1,
                            const float* __restrict__ W2, const float* __restrict__ b2,
                            unsigned* __restrict__ ws) {
    const int t = threadIdx.x;
    if (t < 40) {
        #pragma unroll
        for (int i = 0; i < 5; ++i)
            ws[t * 6 + i] = pkrtz(W1[t * 10 + 2 * i], W1[t * 10 + 2 * i + 1]);
        ws[t * 6 + 5] = __float_as_uint(b1[t]);
    } else if (t < 60) {
        const int p = t - 40;
        #pragma unroll
        for (int o = 0; o < 4; ++o)
            ws[240 + p * 4 + o] = pkrtz(W2[o * 40 + 2 * p], W2[o * 40 + 2 * p + 1]);
    } else if (t < 64) {
        ws[320 + (t - 60)] = __float_as_uint(b2[t - 60]);
    }
}

// ---- main: lean grid-stride (few resident blocks -> x stays L2-resident),
//      R13 body: 1 edge/thread/iter, SGPR weights, nt streams, wave-local
//      LDS staging for coalesced e_tilde stores. No software pipeline. --------
#define TPB 256

__global__ __launch_bounds__(TPB) void edge_mlp_gs_kernel(
    const float* __restrict__ x,
    const float* __restrict__ w,
    const int* __restrict__ src,
    const int* __restrict__ dst,
    const unsigned* __restrict__ W,   // packed weights (uniform -> SGPR/K$)
    float* __restrict__ w_out,
    float* __restrict__ e_tilde,
    int E, int S)
{
    __shared__ float s_et[4][64 * 7];   // per-wave staging (wave-local)

    const int t    = threadIdx.x;
    const int wave = t >> 6;
    const int lane = t & 63;

    for (int base = blockIdx.x * TPB; base < E; base += S) {
        const int e = base + t;

        float m0 = 0.f, m1 = 0.f, m2 = 0.f;
        h2 vm0 = as_h2(0), vm1 = as_h2(0), vm2 = as_h2(0), vm3 = as_h2(0), vm4 = as_h2(0);

        if (e < E) {
            const int si = __builtin_nontemporal_load(src + e);
            const int di = __builtin_nontemporal_load(dst + e);
            m0 = x[3 * si]; m1 = x[3 * si + 1]; m2 = x[3 * si + 2];
            const float d0 = x[3 * di], d1 = x[3 * di + 1], d2 = x[3 * di + 2];
            const f4 wv = __builtin_nontemporal_load((const f4*)w + e);
            vm0 = as_h2(pkrtz(m0, m1));
            vm1 = as_h2(pkrtz(m2, d0));
            vm2 = as_h2(pkrtz(d1, d2));
            vm3 = as_h2(pkrtz(wv.x, wv.y));
            vm4 = as_h2(pkrtz(wv.z, wv.w));
        }

        float o0 = __uint_as_float(W[320]);
        float o1 = __uint_as_float(W[321]);
        float o2 = __uint_as_float(W[322]);
        float o3 = __uint_as_float(W[323]);

        #pragma unroll
        for (int jp = 0; jp < 20; ++jp) {
            const int j0 = 2 * jp, j1 = 2 * jp + 1;
            float h0v = __uint_as_float(W[j0 * 6 + 5]);
            float h1v = __uint_as_float(W[j1 * 6 + 5]);
            h0v = __builtin_amdgcn_fdot2(vm0, as_h2(W[j0 * 6 + 0]), h0v, false);
            h1v = __builtin_amdgcn_fdot2(vm0, as_h2(W[j1 * 6 + 0]), h1v, false);
            h0v = __builtin_amdgcn_fdot2(vm1, as_h2(W[j0 * 6 + 1]), h0v, false);
            h1v = __builtin_amdgcn_fdot2(vm1, as_h2(W[j1 * 6 + 1]), h1v, false);
            h0v = __builtin_amdgcn_fdot2(vm2, as_h2(W[j0 * 6 + 2]), h0v, false);
            h1v = __builtin_amdgcn_fdot2(vm2, as_h2(W[j1 * 6 + 2]), h1v, false);
            h0v = __builtin_amdgcn_fdot2(vm3, as_h2(W[j0 * 6 + 3]), h0v, false);
            h1v = __builtin_amdgcn_fdot2(vm3, as_h2(W[j1 * 6 + 3]), h1v, false);
            h0v = __builtin_amdgcn_fdot2(vm4, as_h2(W[j0 * 6 + 4]), h0v, false);
            h1v = __builtin_amdgcn_fdot2(vm4, as_h2(W[j1 * 6 + 4]), h1v, false);
            h0v = fmaxf(h0v, 0.f);
            h1v = fmaxf(h1v, 0.f);
            const h2 hp = as_h2(pkrtz(h0v, h1v));
            o0 = __builtin_amdgcn_fdot2(hp, as_h2(W[240 + jp * 4 + 0]), o0, false);
            o1 = __builtin_amdgcn_fdot2(hp, as_h2(W[240 + jp * 4 + 1]), o1, false);
            o2 = __builtin_amdgcn_fdot2(hp, as_h2(W[240 + jp * 4 + 2]), o2, false);
            o3 = __builtin_amdgcn_fdot2(hp, as_h2(W[240 + jp * 4 + 3]), o3, false);
        }

        if (e < E) {
            f4 ov; ov.x = o0; ov.y = o1; ov.z = o2; ov.w = o3;
            __builtin_nontemporal_store(ov, (f4*)w_out + e);
        }

        // e_tilde: wave-local LDS exchange (in-order DS pipe within a wave),
        // then 7 coalesced nt dword stores per lane (R13 pattern).
        float* sw = s_et[wave];
        sw[lane * 7 + 0] = m0;
        sw[lane * 7 + 1] = m1;
        sw[lane * 7 + 2] = m2;
        sw[lane * 7 + 3] = o0;
        sw[lane * 7 + 4] = o1;
        sw[lane * 7 + 5] = o2;
        sw[lane * 7 + 6] = o3;

        const int base_e = base + wave * 64;
        const int nvalid = (E - base_e < 64 ? (E - base_e) : 64) * 7;
        const long long fbase = (long long)base_e * 7;
        #pragma unroll
        for (int k = 0; k < 7; ++k) {
            const int idx = lane + 64 * k;
            if (idx < nvalid)
                __builtin_nontemporal_store(sw[idx], e_tilde + fbase + idx);
        }
    }
}

extern "C" void kernel_launch(void* const* d_in, const int* in_sizes, int n_in,
                              void* d_out, int out_size, void* d_ws, size_t ws_size,
                              hipStream_t stream) {
    const float* x  = (const float*)d_in[0];
    const float* w  = (const float*)d_in[1];
    const float* W1 = (const float*)d_in[2];
    const float* b1 = (const float*)d_in[3];
    const float* W2 = (const float*)d_in[4];
    const float* b2 = (const float*)d_in[5];
    const int* src  = (const int*)d_in[6];
    const int* dst  = (const int*)d_in[7];

    const int E = in_sizes[6];

    float* w_out   = (float*)d_out;
    float* e_tilde = w_out + (size_t)E * 4;
    unsigned* ws   = (unsigned*)d_ws;

    prep_kernel<<<1, 64, 0, stream>>>(W1, b1, W2, b2, ws);

    int nblocks = (E + TPB - 1) / TPB;
    if (nblocks > 3125) nblocks = 3125;   // 12.2 blocks/CU; divides E=4M exactly
    const int S = nblocks * TPB;
    edge_mlp_gs_kernel<<<nblocks, TPB, 0, stream>>>(
        x, w, src, dst, ws, w_out, e_tilde, E, S);
}

// Round 19
// 96.399 us; speedup vs baseline: 1.2904x; 1.2904x over previous
//
#include <hip/hip_runtime.h>

typedef __fp16 h2 __attribute__((ext_vector_type(2)));
typedef float f4 __attribute__((ext_vector_type(4)));

static __device__ __forceinline__ unsigned pkrtz(float a, float b) {
    union { h2 v; unsigned u; } cv;
    cv.v = __builtin_amdgcn_cvt_pkrtz(a, b);
    return cv.u;
}
static __device__ __forceinline__ h2 as_h2(unsigned u) {
    union { unsigned u; h2 v; } cv; cv.u = u; return cv.v;
}

// ---- prep: pack weights into f16-pair dwords in d_ws -------------------------
//   [j*6 + i]      i<5 : (W1[j][2i], W1[j][2i+1]) f16 pair       (j in 0..39)
//   [j*6 + 5]          : b1[j] as f32 bits
//   [240 + p*4+o]      : (W2[o][2p], W2[o][2p+1]) f16 pair       (p in 0..19)
//   [320 + o]          : b2[o] as f32 bits
__global__ void prep_kernel(const float* __restrict__ W1, const float* __restrict__ b1,
                            const float* __restrict__ W2, const float* __restrict__ b2,
                            unsigned* __restrict__ ws) {
    const int t = threadIdx.x;
    if (t < 40) {
        #pragma unroll
        for (int i = 0; i < 5; ++i)
            ws[t * 6 + i] = pkrtz(W1[t * 10 + 2 * i], W1[t * 10 + 2 * i + 1]);
        ws[t * 6 + 5] = __float_as_uint(b1[t]);
    } else if (t < 60) {
        const int p = t - 40;
        #pragma unroll
        for (int o = 0; o < 4; ++o)
            ws[240 + p * 4 + o] = pkrtz(W2[o * 40 + 2 * p], W2[o * 40 + 2 * p + 1]);
    } else if (t < 64) {
        ws[320 + (t - 60)] = __float_as_uint(b2[t - 60]);
    }
}

// ---- main: R13 champion body, TPB=512 (4 blocks/CU = full 2048 thr/CU) -------
#define TPB 512
#define NWAVE (TPB / 64)

__global__ __launch_bounds__(TPB) void edge_mlp_nt512_kernel(
    const float* __restrict__ x,
    const float* __restrict__ w,
    const int* __restrict__ src,
    const int* __restrict__ dst,
    const unsigned* __restrict__ W,   // packed weights (uniform access -> SGPR)
    float* __restrict__ w_out,
    float* __restrict__ e_tilde,
    int E)
{
    __shared__ float s_et[NWAVE][64 * 7];   // per-wave e_tilde staging

    const int t    = threadIdx.x;
    const int wave = t >> 6;
    const int lane = t & 63;
    const int e    = blockIdx.x * TPB + t;

    float m0 = 0.f, m1 = 0.f, m2 = 0.f;
    h2 vm0 = as_h2(0), vm1 = as_h2(0), vm2 = as_h2(0), vm3 = as_h2(0), vm4 = as_h2(0);

    if (e < E) {
        // touch-once streams: non-temporal (evict-first keeps x-table cached)
        const int si = __builtin_nontemporal_load(src + e);
        const int di = __builtin_nontemporal_load(dst + e);
        // x-table gathers: normal cached loads (reused across edges)
        m0 = x[3 * si]; m1 = x[3 * si + 1]; m2 = x[3 * si + 2];
        const float d0 = x[3 * di], d1 = x[3 * di + 1], d2 = x[3 * di + 2];
        const f4 wv = __builtin_nontemporal_load((const f4*)w + e);
        vm0 = as_h2(pkrtz(m0, m1));
        vm1 = as_h2(pkrtz(m2, d0));
        vm2 = as_h2(pkrtz(d1, d2));
        vm3 = as_h2(pkrtz(wv.x, wv.y));
        vm4 = as_h2(pkrtz(wv.z, wv.w));
    }

    float o0 = __uint_as_float(W[320]);
    float o1 = __uint_as_float(W[321]);
    float o2 = __uint_as_float(W[322]);
    float o3 = __uint_as_float(W[323]);

    #pragma unroll
    for (int jp = 0; jp < 20; ++jp) {
        const int j0 = 2 * jp, j1 = 2 * jp + 1;
        float h0v = __uint_as_float(W[j0 * 6 + 5]);
        float h1v = __uint_as_float(W[j1 * 6 + 5]);
        h0v = __builtin_amdgcn_fdot2(vm0, as_h2(W[j0 * 6 + 0]), h0v, false);
        h1v = __builtin_amdgcn_fdot2(vm0, as_h2(W[j1 * 6 + 0]), h1v, false);
        h0v = __builtin_amdgcn_fdot2(vm1, as_h2(W[j0 * 6 + 1]), h0v, false);
        h1v = __builtin_amdgcn_fdot2(vm1, as_h2(W[j1 * 6 + 1]), h1v, false);
        h0v = __builtin_amdgcn_fdot2(vm2, as_h2(W[j0 * 6 + 2]), h0v, false);
        h1v = __builtin_amdgcn_fdot2(vm2, as_h2(W[j1 * 6 + 2]), h1v, false);
        h0v = __builtin_amdgcn_fdot2(vm3, as_h2(W[j0 * 6 + 3]), h0v, false);
        h1v = __builtin_amdgcn_fdot2(vm3, as_h2(W[j1 * 6 + 3]), h1v, false);
        h0v = __builtin_amdgcn_fdot2(vm4, as_h2(W[j0 * 6 + 4]), h0v, false);
        h1v = __builtin_amdgcn_fdot2(vm4, as_h2(W[j1 * 6 + 4]), h1v, false);
        h0v = fmaxf(h0v, 0.f);
        h1v = fmaxf(h1v, 0.f);
        const h2 hp = as_h2(pkrtz(h0v, h1v));
        o0 = __builtin_amdgcn_fdot2(hp, as_h2(W[240 + jp * 4 + 0]), o0, false);
        o1 = __builtin_amdgcn_fdot2(hp, as_h2(W[240 + jp * 4 + 1]), o1, false);
        o2 = __builtin_amdgcn_fdot2(hp, as_h2(W[240 + jp * 4 + 2]), o2, false);
        o3 = __builtin_amdgcn_fdot2(hp, as_h2(W[240 + jp * 4 + 3]), o3, false);
    }

    if (e < E) {
        f4 ov; ov.x = o0; ov.y = o1; ov.z = o2; ov.w = o3;
        __builtin_nontemporal_store(ov, (f4*)w_out + e);
    }

    // e_tilde staging -> coalesced nt stores (R13 pattern, incl. barrier)
    float* sw = s_et[wave];
    sw[lane * 7 + 0] = m0;
    sw[lane * 7 + 1] = m1;
    sw[lane * 7 + 2] = m2;
    sw[lane * 7 + 3] = o0;
    sw[lane * 7 + 4] = o1;
    sw[lane * 7 + 5] = o2;
    sw[lane * 7 + 6] = o3;
    __syncthreads();

    const int base_e  = blockIdx.x * TPB + wave * 64;
    const int nvalid  = (E - base_e < 64 ? (E - base_e) : 64) * 7;
    const long long fbase = (long long)base_e * 7;
    #pragma unroll
    for (int k = 0; k < 7; ++k) {
        const int idx = lane + 64 * k;
        if (idx < nvalid)
            __builtin_nontemporal_store(sw[idx], e_tilde + fbase + idx);
    }
}

extern "C" void kernel_launch(void* const* d_in, const int* in_sizes, int n_in,
                              void* d_out, int out_size, void* d_ws, size_t ws_size,
                              hipStream_t stream) {
    const float* x  = (const float*)d_in[0];
    const float* w  = (const float*)d_in[1];
    const float* W1 = (const float*)d_in[2];
    const float* b1 = (const float*)d_in[3];
    const float* W2 = (const float*)d_in[4];
    const float* b2 = (const float*)d_in[5];
    const int* src  = (const int*)d_in[6];
    const int* dst  = (const int*)d_in[7];

    const int E = in_sizes[6];

    float* w_out   = (float*)d_out;
    float* e_tilde = w_out + (size_t)E * 4;
    unsigned* ws   = (unsigned*)d_ws;

    prep_kernel<<<1, 64, 0, stream>>>(W1, b1, W2, b2, ws);

    const int nblocks = (E + TPB - 1) / TPB;
    edge_mlp_nt512_kernel<<<nblocks, TPB, 0, stream>>>(
        x, w, src, dst, ws, w_out, e_tilde, E);
}

// Round 22
// 87.232 us; speedup vs baseline: 1.4260x; 1.1051x over previous
//
#include <hip/hip_runtime.h>

typedef __fp16 h2 __attribute__((ext_vector_type(2)));
typedef float f4 __attribute__((ext_vector_type(4)));

static __device__ __forceinline__ unsigned pkrtz(float a, float b) {
    union { h2 v; unsigned u; } cv;
    cv.v = __builtin_amdgcn_cvt_pkrtz(a, b);
    return cv.u;
}
static __device__ __forceinline__ h2 as_h2(unsigned u) {
    union { unsigned u; h2 v; } cv; cv.u = u; return cv.v;
}

// ---- prep: pack weights into f16-pair dwords in d_ws -------------------------
//   [j*6 + i]      i<5 : (W1[j][2i], W1[j][2i+1]) f16 pair       (j in 0..39)
//   [j*6 + 5]          : b1[j] as f32 bits
//   [240 + p*4+o]      : (W2[o][2p], W2[o][2p+1]) f16 pair       (p in 0..19)
//   [320 + o]          : b2[o] as f32 bits
__global__ void prep_kernel(const float* __restrict__ W1, const float* __restrict__ b1,
                            const float* __restrict__ W2, const float* __restrict__ b2,
                            unsigned* __restrict__ ws) {
    const int t = threadIdx.x;
    if (t < 40) {
        #pragma unroll
        for (int i = 0; i < 5; ++i)
            ws[t * 6 + i] = pkrtz(W1[t * 10 + 2 * i], W1[t * 10 + 2 * i + 1]);
        ws[t * 6 + 5] = __float_as_uint(b1[t]);
    } else if (t < 60) {
        const int p = t - 40;
        #pragma unroll
        for (int o = 0; o < 4; ++o)
            ws[240 + p * 4 + o] = pkrtz(W2[o * 40 + 2 * p], W2[o * 40 + 2 * p + 1]);
    } else if (t < 64) {
        ws[320 + (t - 60)] = __float_as_uint(b2[t - 60]);
    }
}

// ---- main: champion body (R13/R19), TPB=1024 (2 blocks/CU, full occupancy) ---
#define TPB 1024
#define NWAVE (TPB / 64)

__global__ __launch_bounds__(TPB) void edge_mlp_nt1k_kernel(
    const float* __restrict__ x,
    const float* __restrict__ w,
    const int* __restrict__ src,
    const int* __restrict__ dst,
    const unsigned* __restrict__ W,   // packed weights (uniform access -> SGPR)
    float* __restrict__ w_out,
    float* __restrict__ e_tilde,
    int E)
{
    __shared__ float s_et[NWAVE][64 * 7];   // per-wave e_tilde staging

    const int t    = threadIdx.x;
    const int wave = t >> 6;
    const int lane = t & 63;
    const int e    = blockIdx.x * TPB + t;

    float m0 = 0.f, m1 = 0.f, m2 = 0.f;
    h2 vm0 = as_h2(0), vm1 = as_h2(0), vm2 = as_h2(0), vm3 = as_h2(0), vm4 = as_h2(0);

    if (e < E) {
        // touch-once streams: non-temporal (evict-first keeps x-table cached)
        const int si = __builtin_nontemporal_load(src + e);
        const int di = __builtin_nontemporal_load(dst + e);
        // x-table gathers: normal cached loads (reused across edges)
        m0 = x[3 * si]; m1 = x[3 * si + 1]; m2 = x[3 * si + 2];
        const float d0 = x[3 * di], d1 = x[3 * di + 1], d2 = x[3 * di + 2];
        const f4 wv = __builtin_nontemporal_load((const f4*)w + e);
        vm0 = as_h2(pkrtz(m0, m1));
        vm1 = as_h2(pkrtz(m2, d0));
        vm2 = as_h2(pkrtz(d1, d2));
        vm3 = as_h2(pkrtz(wv.x, wv.y));
        vm4 = as_h2(pkrtz(wv.z, wv.w));
    }

    float o0 = __uint_as_float(W[320]);
    float o1 = __uint_as_float(W[321]);
    float o2 = __uint_as_float(W[322]);
    float o3 = __uint_as_float(W[323]);

    #pragma unroll
    for (int jp = 0; jp < 20; ++jp) {
        const int j0 = 2 * jp, j1 = 2 * jp + 1;
        float h0v = __uint_as_float(W[j0 * 6 + 5]);
        float h1v = __uint_as_float(W[j1 * 6 + 5]);
        h0v = __builtin_amdgcn_fdot2(vm0, as_h2(W[j0 * 6 + 0]), h0v, false);
        h1v = __builtin_amdgcn_fdot2(vm0, as_h2(W[j1 * 6 + 0]), h1v, false);
        h0v = __builtin_amdgcn_fdot2(vm1, as_h2(W[j0 * 6 + 1]), h0v, false);
        h1v = __builtin_amdgcn_fdot2(vm1, as_h2(W[j1 * 6 + 1]), h1v, false);
        h0v = __builtin_amdgcn_fdot2(vm2, as_h2(W[j0 * 6 + 2]), h0v, false);
        h1v = __builtin_amdgcn_fdot2(vm2, as_h2(W[j1 * 6 + 2]), h1v, false);
        h0v = __builtin_amdgcn_fdot2(vm3, as_h2(W[j0 * 6 + 3]), h0v, false);
        h1v = __builtin_amdgcn_fdot2(vm3, as_h2(W[j1 * 6 + 3]), h1v, false);
        h0v = __builtin_amdgcn_fdot2(vm4, as_h2(W[j0 * 6 + 4]), h0v, false);
        h1v = __builtin_amdgcn_fdot2(vm4, as_h2(W[j1 * 6 + 4]), h1v, false);
        h0v = fmaxf(h0v, 0.f);
        h1v = fmaxf(h1v, 0.f);
        const h2 hp = as_h2(pkrtz(h0v, h1v));
        o0 = __builtin_amdgcn_fdot2(hp, as_h2(W[240 + jp * 4 + 0]), o0, false);
        o1 = __builtin_amdgcn_fdot2(hp, as_h2(W[240 + jp * 4 + 1]), o1, false);
        o2 = __builtin_amdgcn_fdot2(hp, as_h2(W[240 + jp * 4 + 2]), o2, false);
        o3 = __builtin_amdgcn_fdot2(hp, as_h2(W[240 + jp * 4 + 3]), o3, false);
    }

    if (e < E) {
        f4 ov; ov.x = o0; ov.y = o1; ov.z = o2; ov.w = o3;
        __builtin_nontemporal_store(ov, (f4*)w_out + e);
    }

    // e_tilde staging -> coalesced nt stores (champion pattern, incl. barrier)
    float* sw = s_et[wave];
    sw[lane * 7 + 0] = m0;
    sw[lane * 7 + 1] = m1;
    sw[lane * 7 + 2] = m2;
    sw[lane * 7 + 3] = o0;
    sw[lane * 7 + 4] = o1;
    sw[lane * 7 + 5] = o2;
    sw[lane * 7 + 6] = o3;
    __syncthreads();

    const int base_e  = blockIdx.x * TPB + wave * 64;
    const int nvalid  = (E - base_e < 64 ? (E - base_e) : 64) * 7;
    const long long fbase = (long long)base_e * 7;
    #pragma unroll
    for (int k = 0; k < 7; ++k) {
        const int idx = lane + 64 * k;
        if (idx < nvalid)
            __builtin_nontemporal_store(sw[idx], e_tilde + fbase + idx);
    }
}

extern "C" void kernel_launch(void* const* d_in, const int* in_sizes, int n_in,
                              void* d_out, int out_size, void* d_ws, size_t ws_size,
                              hipStream_t stream) {
    const float* x  = (const float*)d_in[0];
    const float* w  = (const float*)d_in[1];
    const float* W1 = (const float*)d_in[2];
    const float* b1 = (const float*)d_in[3];
    const float* W2 = (const float*)d_in[4];
    const float* b2 = (const float*)d_in[5];
    const int* src  = (const int*)d_in[6];
    const int* dst  = (const int*)d_in[7];

    const int E = in_sizes[6];

    float* w_out   = (float*)d_out;
    float* e_tilde = w_out + (size_t)E * 4;
    unsigned* ws   = (unsigned*)d_ws;

    prep_kernel<<<1, 64, 0, stream>>>(W1, b1, W2, b2, ws);

    const int nblocks = (E + TPB - 1) / TPB;
    edge_mlp_nt1k_kernel<<<nblocks, TPB, 0, stream>>>(
        x, w, src, dst, ws, w_out, e_tilde, E);
}